// Round 9
// baseline (306.237 us; speedup 1.0000x reference)
//
#include <hip/hip_runtime.h>

// LSTM cell: gates = [x|h] @ [Wx|Wh]^T + b -> sigmoid/tanh elementwise.
// Round 8 design (resubmit; broker timeout — never benched):
//   32x32x16 MFMA (half the instructions, 2x LDS intensity/instr, faster pipe),
//   256x256 tile, 8 waves (2Mx4N), BK=32, 3-ring LDS (144KB), counted vmcnt(6),
//   2 phases x 16 MFMA per K-tile, unroll-by-3 (literal LDS offsets, no %3),
//   gate interleave pos=[i,o,f,c] + shfl_xor(16) in-register epilogue.
// Math: 2-term hi/lo split (A_hi*B_hi + A_hi*B_lo), f32 accumulate.

typedef __attribute__((ext_vector_type(4)))  float  f32x4;
typedef __attribute__((ext_vector_type(16))) float  f32x16;
typedef __attribute__((ext_vector_type(8)))  __bf16 bf16x8;
typedef __attribute__((ext_vector_type(8)))  short  s16x8;

#define HID    1024
#define BATCH  4096
#define KDIM   2048
#define PANEL_STRIDE (128 * KDIM)   // shorts per 128-row panel plane
#define KT_STRIDE    4096           // shorts per (panel,kt) chunk: 4 g * 128 r * 8 e

// ---------------- fp32 <-> bf16 (round-to-nearest-even) ----------------
__device__ __forceinline__ unsigned short f2bf(float f) {
  unsigned u = __builtin_bit_cast(unsigned, f);
  u += 0x7FFFu + ((u >> 16) & 1u);
  return (unsigned short)(u >> 16);
}
__device__ __forceinline__ float bf2f(unsigned short s) {
  return __builtin_bit_cast(float, (unsigned)s << 16);
}

// ---------------- 1) convert: fp32 -> plane-tiled bf16 (A: hi; B: hi+lo) ----------------
// ws element (panel p, kt, g, r, e) <=> matrix (row = p*128+r, k = kt*32 + g*8 + e)
// B row n' = (j>>4)*64 + pos*16 + (j&15), pos order [i,o,f,c] (for 32x32 epilogue pairing)
__global__ void convert_kernel(
    const float* __restrict__ x,   const float* __restrict__ h,
    const float* __restrict__ Wix, const float* __restrict__ Wfx,
    const float* __restrict__ Wox, const float* __restrict__ Wcx,
    const float* __restrict__ Wih, const float* __restrict__ Wfh,
    const float* __restrict__ Woh, const float* __restrict__ Wch,
    const float* __restrict__ bix, const float* __restrict__ bfx,
    const float* __restrict__ box, const float* __restrict__ bcx,
    const float* __restrict__ bih, const float* __restrict__ bfh,
    const float* __restrict__ boh, const float* __restrict__ bch,
    short* __restrict__ Ahi, short* __restrict__ Bhi, short* __restrict__ Blo,
    float* __restrict__ bias)
{
  const int bid = blockIdx.x;
  const int t   = threadIdx.x;
  const int r   = t >> 1;
  const int kh  = t & 1;
  const bool isA = bid < 2048;
  const int pb = isA ? bid : (bid - 2048);
  const int p  = pb >> 6;
  const int kt = pb & 63;
  const int kk = kt * 32 + kh * 16;   // 16-aligned, never straddles the x|h boundary

  const float* srow;
  if (isA) {
    const int m = p * 128 + r;
    srow = (kk < 1024) ? (x + (size_t)m * 1024 + kk)
                       : (h + (size_t)m * 1024 + (kk - 1024));
  } else {
    const int np = p * 128 + r;
    const int j = ((np >> 6) << 4) + (np & 15);
    const int pos = (np >> 4) & 3;   // 0=i 1=o 2=f 3=c
    const float* wx = (pos == 0) ? Wix : (pos == 1) ? Wox : (pos == 2) ? Wfx : Wcx;
    const float* wh = (pos == 0) ? Wih : (pos == 1) ? Woh : (pos == 2) ? Wfh : Wch;
    srow = (kk < 1024) ? (wx + (size_t)j * 1024 + kk)
                       : (wh + (size_t)j * 1024 + (kk - 1024));
    if (kt == 0 && t < 128) {          // combined bias in n' order
      const int np2 = p * 128 + t;
      const int j2 = ((np2 >> 6) << 4) + (np2 & 15);
      const int p2 = (np2 >> 4) & 3;
      const float* bx  = (p2 == 0) ? bix : (p2 == 1) ? box : (p2 == 2) ? bfx : bcx;
      const float* bh2 = (p2 == 0) ? bih : (p2 == 1) ? boh : (p2 == 2) ? bfh : bch;
      bias[np2] = bx[j2] + bh2[j2];
    }
  }
  f32x4 v0 = ((const f32x4*)srow)[0];
  f32x4 v1 = ((const f32x4*)srow)[1];
  f32x4 v2 = ((const f32x4*)srow)[2];
  f32x4 v3 = ((const f32x4*)srow)[3];
  s16x8 h0, l0, h1, l1;
  #pragma unroll
  for (int c = 0; c < 8; ++c) {
    float f0 = (c < 4) ? v0[c & 3] : v1[c & 3];
    unsigned short a = f2bf(f0);
    h0[c] = (short)a; l0[c] = (short)f2bf(f0 - bf2f(a));
    float f1 = (c < 4) ? v2[c & 3] : v3[c & 3];
    unsigned short b = f2bf(f1);
    h1[c] = (short)b; l1[c] = (short)f2bf(f1 - bf2f(b));
  }
  const size_t base = ((size_t)p * 64 + kt) * KT_STRIDE + (size_t)(kh * 2) * 1024 + (size_t)r * 8;
  if (isA) {
    *(s16x8*)(Ahi + base) = h0; *(s16x8*)(Ahi + base + 1024) = h1;
  } else {
    *(s16x8*)(Bhi + base) = h0; *(s16x8*)(Bhi + base + 1024) = h1;
    *(s16x8*)(Blo + base) = l0; *(s16x8*)(Blo + base + 1024) = l1;
  }
}

// ---------------- 2) fused GEMM + in-register LSTM epilogue (32x32x16) ----------------
#define GLD16(SRC, DST) \
  __builtin_amdgcn_global_load_lds((const __attribute__((address_space(1))) void*)(SRC), \
                                   (__attribute__((address_space(3))) void*)(DST), 16, 0, 0)

__device__ __forceinline__ float sigmoid_f(float v) { return 1.f / (1.f + __expf(-v)); }
__device__ __forceinline__ float tanh_f(float v) {
  float t = __expf(-2.f * fabsf(v));
  float r = (1.f - t) / (1.f + t);
  return copysignf(r, v);
}

__global__ __launch_bounds__(512, 2) void gemm_fused_kernel(
    const short* __restrict__ Ahi,
    const short* __restrict__ Bhi, const short* __restrict__ Blo,
    const float* __restrict__ bias, const float* __restrict__ c1,
    float* __restrict__ out)
{
  // 3-deep ring; buffer = A[2 chunks] | Bhi[2] | Blo[2], chunk 4096 shorts
  // in plane layout [4 g][128 r][8 e]. 3 * 48 KB = 144 KB.
  __shared__ __align__(16) short sA[3 * 24576];

  const int tid = threadIdx.x, wave = tid >> 6, lane = tid & 63;
  int bid = blockIdx.x;
  bid = (bid & 7) * 32 + (bid >> 3);         // XCD-aware swizzle (256 % 8 == 0)
  const int by = bid >> 4, bx = bid & 15;    // 16 x 16 tile grid
  const int wm = wave >> 2, wn = wave & 3;   // 2M x 4N waves
  const int l31 = lane & 31, lhi = lane >> 5;
  const int loff = lane * 8;

  f32x16 acc[4][2];
  #pragma unroll
  for (int i = 0; i < 4; ++i)
    #pragma unroll
    for (int j = 0; j < 2; ++j)
      #pragma unroll
      for (int r = 0; r < 16; ++r) acc[i][j][r] = 0.f;

  // 6 staging descriptors per wave (flat idx = wave*6+i; pl 0:A 1:Bhi 2:Blo)
#define MKQ(Q, D, IDX) {                                                     \
    const int pl_ = (IDX) >> 4, ch_ = ((IDX) >> 3) & 1, ss_ = (IDX) & 7;     \
    const short* pb_ = (pl_ == 0) ? (Ahi + (size_t)(2*by + ch_) * PANEL_STRIDE) \
                     : (pl_ == 1) ? (Bhi + (size_t)(2*bx + ch_) * PANEL_STRIDE) \
                                  : (Blo + (size_t)(2*bx + ch_) * PANEL_STRIDE); \
    Q = pb_ + ss_ * 512 + loff;                                              \
    D = pl_ * 8192 + ch_ * 4096 + ss_ * 512; }

  const short *q0, *q1, *q2, *q3, *q4, *q5;
  int d0, d1, d2, d3, d4, d5;
  const int ix0 = wave * 6;
  MKQ(q0, d0, ix0)     MKQ(q1, d1, ix0 + 1) MKQ(q2, d2, ix0 + 2)
  MKQ(q3, d3, ix0 + 3) MKQ(q4, d4, ix0 + 4) MKQ(q5, d5, ix0 + 5)

#define STG(Q, D, KT2, SB2) GLD16((Q) + (size_t)(KT2) * KT_STRIDE, &sA[(SB2) + (D)])

#define BODY(SB, SB2, KT2, VMN, DS) {                                         \
    asm volatile("s_waitcnt vmcnt(" #VMN ")" ::: "memory");                   \
    __builtin_amdgcn_s_barrier();                                             \
    bf16x8 av[2][2], bfr[2][2][2];                                            \
    _Pragma("unroll") for (int kh = 0; kh < 2; ++kh) {                        \
      const int g2o = (SB) + (2*kh + lhi) * 1024;                             \
      _Pragma("unroll") for (int tm = 0; tm < 2; ++tm)                        \
        av[tm][kh] = *(const bf16x8*)&sA[g2o + wm*4096 + (tm*32 + l31)*8];    \
      _Pragma("unroll") for (int tn = 0; tn < 2; ++tn) {                      \
        const int bo_ = g2o + (wn>>1)*4096 + ((wn&1)*64 + tn*32 + l31)*8;     \
        bfr[tn][kh][0] = *(const bf16x8*)&sA[bo_ + 8192];                     \
        bfr[tn][kh][1] = *(const bf16x8*)&sA[bo_ + 16384];                    \
      }                                                                       \
    }                                                                         \
    if (DS) { STG(q0,d0,KT2,SB2); STG(q1,d1,KT2,SB2); STG(q2,d2,KT2,SB2); }   \
    __builtin_amdgcn_s_barrier();                                             \
    __builtin_amdgcn_s_setprio(1);                                            \
    _Pragma("unroll") for (int kh = 0; kh < 2; ++kh)                          \
      _Pragma("unroll") for (int tm = 0; tm < 2; ++tm)                        \
        _Pragma("unroll") for (int tn = 0; tn < 2; ++tn)                      \
          acc[tm][tn] = __builtin_amdgcn_mfma_f32_32x32x16_bf16(              \
              av[tm][kh], bfr[tn][kh][0], acc[tm][tn], 0, 0, 0);              \
    _Pragma("unroll") for (int kh = 0; kh < 2; ++kh)                          \
      _Pragma("unroll") for (int tm = 0; tm < 2; ++tm)                        \
        _Pragma("unroll") for (int tn = 0; tn < 2; ++tn)                      \
          acc[tm][tn] = __builtin_amdgcn_mfma_f32_32x32x16_bf16(              \
              av[tm][kh], bfr[tn][kh][1], acc[tm][tn], 0, 0, 0);              \
    __builtin_amdgcn_s_setprio(0);                                            \
    __builtin_amdgcn_s_barrier();                                             \
    _Pragma("unroll") for (int kh = 0; kh < 2; ++kh) {                        \
      const int g2o = (SB) + (2*kh + lhi) * 1024;                             \
      _Pragma("unroll") for (int tm = 0; tm < 2; ++tm)                        \
        av[tm][kh] = *(const bf16x8*)&sA[g2o + wm*4096 + ((tm+2)*32 + l31)*8];\
    }                                                                         \
    if (DS) { STG(q3,d3,KT2,SB2); STG(q4,d4,KT2,SB2); STG(q5,d5,KT2,SB2); }   \
    __builtin_amdgcn_s_barrier();                                             \
    __builtin_amdgcn_s_setprio(1);                                            \
    _Pragma("unroll") for (int kh = 0; kh < 2; ++kh)                          \
      _Pragma("unroll") for (int tm = 0; tm < 2; ++tm)                        \
        _Pragma("unroll") for (int tn = 0; tn < 2; ++tn)                      \
          acc[tm+2][tn] = __builtin_amdgcn_mfma_f32_32x32x16_bf16(            \
              av[tm][kh], bfr[tn][kh][0], acc[tm+2][tn], 0, 0, 0);            \
    _Pragma("unroll") for (int kh = 0; kh < 2; ++kh)                          \
      _Pragma("unroll") for (int tm = 0; tm < 2; ++tm)                        \
        _Pragma("unroll") for (int tn = 0; tn < 2; ++tn)                      \
          acc[tm+2][tn] = __builtin_amdgcn_mfma_f32_32x32x16_bf16(            \
              av[tm][kh], bfr[tn][kh][1], acc[tm+2][tn], 0, 0, 0);            \
    __builtin_amdgcn_s_setprio(0);                                            \
  }

  // prologue: stage kt=0 -> buf0, kt=1 -> buf1
  STG(q0,d0,0,0); STG(q1,d1,0,0); STG(q2,d2,0,0);
  STG(q3,d3,0,0); STG(q4,d4,0,0); STG(q5,d5,0,0);
  STG(q0,d0,1,24576); STG(q1,d1,1,24576); STG(q2,d2,1,24576);
  STG(q3,d3,1,24576); STG(q4,d4,1,24576); STG(q5,d5,1,24576);

  for (int t3 = 0; t3 < 60; t3 += 3) {      // kt = t3, t3+1, t3+2  (0..59)
    BODY(0,     49152, t3 + 2, 6, true)
    BODY(24576, 0,     t3 + 3, 6, true)
    BODY(49152, 24576, t3 + 4, 6, true)
  }
  BODY(0,     49152, 62, 6, true)           // kt=60, stage 62
  BODY(24576, 0,     63, 6, true)           // kt=61, stage 63
  BODY(49152, 0, 0, 6, false)               // kt=62
  BODY(0,     0, 0, 0, false)               // kt=63

  // ---- in-register epilogue ----
  // C 32x32 layout: col = lane&31, row = (reg&3) + 8*(reg>>2) + 4*(lane>>5).
  // Block cols [0,16):i [16,32):o [32,48):f [48,64):c (per 64-col j-group).
  // lane l31<16: tn0=i, tn1=f; lane l31>=16 (same jj): tn0=o, tn1=c. shfl_xor(16) pairs them.
  const int jj = l31 & 15;
  const int n0 = bx * 256 + wn * 64;
  const int j  = bx * 64 + wn * 16 + jj;
  const float b_i = bias[n0 + jj];
  const float b_o = bias[n0 + 16 + jj];
  const float b_f = bias[n0 + 32 + jj];
  const float b_c = bias[n0 + 48 + jj];
  const bool lo = (l31 < 16);
  const int rbase = by * 256 + wm * 128 + 4 * lhi;
  #pragma unroll
  for (int tm = 0; tm < 4; ++tm)
    #pragma unroll
    for (int r = 0; r < 16; ++r) {
      const int m = rbase + tm * 32 + (r & 3) + 8 * (r >> 2);
      const float V0 = acc[tm][0][r], V1 = acc[tm][1][r];
      const float p0 = __shfl_xor(V0, 16);
      const float p1 = __shfl_xor(V1, 16);
      const float gi = lo ? V0 : p0, gf = lo ? V1 : p1;
      const float go = lo ? p0 : V0, gc = lo ? p1 : V1;
      const float I  = sigmoid_f(gi + b_i);
      const float F  = sigmoid_f(gf + b_f);
      const float O  = sigmoid_f(go + b_o);
      const float Ct = tanh_f(gc + b_c);
      const float cc = F * c1[(size_t)m * HID + j] + I * Ct;
      if (lo) {
        out[(size_t)m * HID + j]                       = O * tanh_f(cc);  // h
        out[(size_t)BATCH * HID + (size_t)m * HID + j] = cc;              // c
      }
    }
  #undef BODY
  #undef STG
  #undef MKQ
}

// ---------------- launch ----------------
extern "C" void kernel_launch(void* const* d_in, const int* in_sizes, int n_in,
                              void* d_out, int out_size, void* d_ws, size_t ws_size,
                              hipStream_t stream) {
  const float* x    = (const float*)d_in[0];
  const float* h1   = (const float*)d_in[1];
  const float* c1   = (const float*)d_in[2];
  const float* W_ix = (const float*)d_in[3];  const float* b_ix = (const float*)d_in[4];
  const float* W_ih = (const float*)d_in[5];  const float* b_ih = (const float*)d_in[6];
  const float* W_fx = (const float*)d_in[7];  const float* b_fx = (const float*)d_in[8];
  const float* W_fh = (const float*)d_in[9];  const float* b_fh = (const float*)d_in[10];
  const float* W_ox = (const float*)d_in[11]; const float* b_ox = (const float*)d_in[12];
  const float* W_oh = (const float*)d_in[13]; const float* b_oh = (const float*)d_in[14];
  const float* W_cx = (const float*)d_in[15]; const float* b_cx = (const float*)d_in[16];
  const float* W_ch = (const float*)d_in[17]; const float* b_ch = (const float*)d_in[18];

  // ws: Ahi | Bhi | Blo (16MB each, plane-tiled) | bias_sum (16KB)
  short* Ahi = (short*)d_ws;
  short* Bhi = Ahi + (size_t)8 * 1024 * 1024;
  short* Blo = Bhi + (size_t)8 * 1024 * 1024;
  float* bias = (float*)(Blo + (size_t)8 * 1024 * 1024);

  convert_kernel<<<4096, 256, 0, stream>>>(x, h1,
      W_ix, W_fx, W_ox, W_cx, W_ih, W_fh, W_oh, W_ch,
      b_ix, b_fx, b_ox, b_cx, b_ih, b_fh, b_oh, b_ch,
      Ahi, Bhi, Blo, bias);

  gemm_fused_kernel<<<256, 512, 0, stream>>>(Ahi, Bhi, Blo, bias, c1, (float*)d_out);
}